// Round 1
// baseline (76.303 us; speedup 1.0000x reference)
//
#include <hip/hip_runtime.h>
#include <math.h>

#define EPSF 1e-6f
#define N_PTS 1024
#define BT 32

// ---------------------------------------------------------------------------
// Stage kernel: grid (4 ref-chunks, 32 batches, 2 directions), block 256.
// Each thread owns Q=4 query points; each block covers a 256-point ref chunk
// staged in LDS as float4 (one ds_read_b128 per ref point, broadcast across
// the wave, amortized over 4 queries -> LDS pipe ~5us < VALU ~6us).
// Writes per-query partial min squared distance to ws[dirb][q][chunk].
// ---------------------------------------------------------------------------
__global__ __launch_bounds__(256) void chamfer_stage(
    const float* __restrict__ x, const float* __restrict__ y,
    float* __restrict__ ws) {
  const int t   = threadIdx.x;
  const int rc  = blockIdx.x;   // ref chunk 0..3 (256 refs each)
  const int b   = blockIdx.y;   // batch 0..31
  const int dir = blockIdx.z;   // 0: query=x, ref=y (min1) ; 1: swapped (min2)

  const float* q = dir ? y : x;
  const float* r = dir ? x : y;
  const float* qb = q + (size_t)b * N_PTS * 3;
  const float* rb = r + (size_t)b * N_PTS * 3 + (size_t)rc * 256 * 3;

  __shared__ float4 s[256];
  {
    float rx = rb[t * 3 + 0];
    float ry = rb[t * 3 + 1];
    float rz = rb[t * 3 + 2];
    s[t] = make_float4(rx, ry, rz, 0.0f);
  }
  __syncthreads();

  float qx[4], qy[4], qz[4], m[4];
#pragma unroll
  for (int k = 0; k < 4; ++k) {
    const int j = t + 256 * k;
    qx[k] = qb[j * 3 + 0];
    qy[k] = qb[j * 3 + 1];
    qz[k] = qb[j * 3 + 2];
    m[k] = 3.4e38f;
  }

#pragma unroll 4
  for (int i = 0; i < 256; ++i) {
    const float4 rp = s[i];
#pragma unroll
    for (int k = 0; k < 4; ++k) {
      const float dx = qx[k] - rp.x;
      const float dy = qy[k] - rp.y;
      const float dz = qz[k] - rp.z;
      const float sq = dx * dx + dy * dy + dz * dz;
      m[k] = fminf(m[k], sq);
    }
  }

  float* wbase = ws + (size_t)(dir * BT + b) * (N_PTS * 4);
#pragma unroll
  for (int k = 0; k < 4; ++k) {
    const int j = t + 256 * k;
    wbase[j * 4 + rc] = m[k];
  }
}

// ---------------------------------------------------------------------------
// Reduce kernel: 65536 (dirb, query) entries; min over the 4 ref-chunk
// partials (one aligned float4 load), sqrt(eps+min), block-sum, one
// atomicAdd per block scaled by 1/32768 (= 1/(BT*N); both directions sum
// into the same scalar, giving mean(min1)+mean(min2)).
// ---------------------------------------------------------------------------
__global__ __launch_bounds__(256) void chamfer_reduce(
    const float* __restrict__ ws, float* __restrict__ out) {
  const int g = blockIdx.x * 256 + threadIdx.x;  // 0..65535
  const float4 p = ((const float4*)ws)[g];
  const float msq = fminf(fminf(p.x, p.y), fminf(p.z, p.w));
  float d = sqrtf(EPSF + msq);

  for (int off = 32; off > 0; off >>= 1) d += __shfl_down(d, off, 64);

  __shared__ float wsum[4];
  const int lane = threadIdx.x & 63;
  const int w = threadIdx.x >> 6;
  if (lane == 0) wsum[w] = d;
  __syncthreads();
  if (threadIdx.x == 0) {
    const float bsum = wsum[0] + wsum[1] + wsum[2] + wsum[3];
    atomicAdd(out, bsum * (1.0f / 32768.0f));
  }
}

// ---------------------------------------------------------------------------
// Fallback (if ws_size < 1 MB): full-ref LDS tile, 1 query/thread,
// atomicAdd straight into out. ~LDS-pipe-bound (~20us) but correct and
// workspace-free.
// ---------------------------------------------------------------------------
__global__ __launch_bounds__(256) void chamfer_simple(
    const float* __restrict__ x, const float* __restrict__ y,
    float* __restrict__ out) {
  const int t   = threadIdx.x;
  const int qc  = blockIdx.x;   // query chunk 0..3
  const int b   = blockIdx.y;
  const int dir = blockIdx.z;

  const float* q = dir ? y : x;
  const float* r = dir ? x : y;
  const float* qb = q + (size_t)b * N_PTS * 3;
  const float* rb = r + (size_t)b * N_PTS * 3;

  __shared__ float4 s[N_PTS];
  for (int i = t; i < N_PTS; i += 256) {
    s[i] = make_float4(rb[i * 3], rb[i * 3 + 1], rb[i * 3 + 2], 0.0f);
  }
  __syncthreads();

  const int j = qc * 256 + t;
  const float qx = qb[j * 3], qy = qb[j * 3 + 1], qz = qb[j * 3 + 2];
  float m = 3.4e38f;
#pragma unroll 8
  for (int i = 0; i < N_PTS; ++i) {
    const float4 rp = s[i];
    const float dx = qx - rp.x;
    const float dy = qy - rp.y;
    const float dz = qz - rp.z;
    m = fminf(m, dx * dx + dy * dy + dz * dz);
  }
  float d = sqrtf(EPSF + m);

  for (int off = 32; off > 0; off >>= 1) d += __shfl_down(d, off, 64);

  __shared__ float wsum[4];
  if ((t & 63) == 0) wsum[t >> 6] = d;
  __syncthreads();
  if (t == 0) {
    atomicAdd(out, (wsum[0] + wsum[1] + wsum[2] + wsum[3]) * (1.0f / 32768.0f));
  }
}

extern "C" void kernel_launch(void* const* d_in, const int* in_sizes, int n_in,
                              void* d_out, int out_size, void* d_ws, size_t ws_size,
                              hipStream_t stream) {
  const float* x = (const float*)d_in[0];
  const float* y = (const float*)d_in[1];
  float* out = (float*)d_out;

  // d_out is re-poisoned to 0xAA before every timed replay; zero it first.
  hipMemsetAsync(out, 0, sizeof(float) * out_size, stream);

  const size_t ws_need = (size_t)2 * BT * N_PTS * 4 * sizeof(float);  // 1 MiB
  if (ws_size >= ws_need) {
    chamfer_stage<<<dim3(4, BT, 2), 256, 0, stream>>>(x, y, (float*)d_ws);
    chamfer_reduce<<<dim3(256), 256, 0, stream>>>((const float*)d_ws, out);
  } else {
    chamfer_simple<<<dim3(4, BT, 2), 256, 0, stream>>>(x, y, out);
  }
}

// Round 2
// 71.866 us; speedup vs baseline: 1.0617x; 1.0617x over previous
//
#include <hip/hip_runtime.h>
#include <math.h>

#define EPSF 1e-6f
#define N_PTS 1024
#define BT 32
#define RC 16          // ref chunks per (batch, dir); chunk = 64 points
#define CHUNK 64

// ---------------------------------------------------------------------------
// Stage: grid (16 ref-chunks, 32 batches, 2 directions) x 128 threads.
// Q=8 queries/thread (block covers the full 1024 queries of its batch).
// Ref chunk (64 pts) staged in LDS as float4(rx,ry,rz,r2); one broadcast
// ds_read_b128 per ref serves 8 queries. Inner pair = 5 VALU ops:
// cross(mul+2fma), fma(-2,cross,r2), min. q2 is hoisted out of the min.
// 1024 blocks -> 4 blocks/CU, 8 waves/CU: VALU-bound ~4.3us/CU.
// Writes clamped min-sq partials to ws[(dirb*RC+rc)*1024 + q] (coalesced).
// ---------------------------------------------------------------------------
__global__ __launch_bounds__(128) void chamfer_stage(
    const float* __restrict__ x, const float* __restrict__ y,
    float* __restrict__ ws) {
  const int t   = threadIdx.x;
  const int rc  = blockIdx.x;   // 0..15
  const int b   = blockIdx.y;   // 0..31
  const int dir = blockIdx.z;   // 0: query=x ref=y ; 1: swapped

  const float* qarr = dir ? y : x;
  const float* rarr = dir ? x : y;
  const float* qb = qarr + (size_t)b * (N_PTS * 3);
  const float* rb = rarr + (size_t)b * (N_PTS * 3) + (size_t)rc * (CHUNK * 3);

  __shared__ float4 s[CHUNK];
  if (t < CHUNK) {
    const float rx = rb[t * 3 + 0];
    const float ry = rb[t * 3 + 1];
    const float rz = rb[t * 3 + 2];
    s[t] = make_float4(rx, ry, rz, rx * rx + ry * ry + rz * rz);
  }
  __syncthreads();

  float qx[8], qy[8], qz[8], q2[8], m[8];
#pragma unroll
  for (int k = 0; k < 8; ++k) {
    const int j = t + 128 * k;
    qx[k] = qb[j * 3 + 0];
    qy[k] = qb[j * 3 + 1];
    qz[k] = qb[j * 3 + 2];
    q2[k] = qx[k] * qx[k] + qy[k] * qy[k] + qz[k] * qz[k];
    m[k] = 3.4e38f;
  }

#pragma unroll 4
  for (int i = 0; i < CHUNK; ++i) {
    const float4 rp = s[i];
#pragma unroll
    for (int k = 0; k < 8; ++k) {
      const float cross = qx[k] * rp.x + qy[k] * rp.y + qz[k] * rp.z;
      const float v = fmaf(-2.0f, cross, rp.w);  // r2 - 2*q.r
      m[k] = fminf(m[k], v);
    }
  }

  float* wbase = ws + ((size_t)(dir * BT + b) * RC + rc) * N_PTS;
#pragma unroll
  for (int k = 0; k < 8; ++k) {
    const int j = t + 128 * k;
    wbase[j] = fmaxf(q2[k] + m[k], 0.0f);  // clamp commutes with min
  }
}

// ---------------------------------------------------------------------------
// Reduce: 65536 (dirb, query) entries, 256 blocks x 256 threads.
// 16 coalesced loads/thread (stride 1024 over rc), min, sqrt(eps+.),
// wave+block sum, one scaled atomicAdd per block.
// ---------------------------------------------------------------------------
__global__ __launch_bounds__(256) void chamfer_reduce(
    const float* __restrict__ ws, float* __restrict__ out) {
  const int g = blockIdx.x * 256 + threadIdx.x;  // 0..65535
  const int dirb = g >> 10;
  const int q = g & (N_PTS - 1);
  const float* base = ws + (size_t)dirb * RC * N_PTS + q;
  float mn = base[0];
#pragma unroll
  for (int r = 1; r < RC; ++r) mn = fminf(mn, base[r * N_PTS]);
  float d = sqrtf(EPSF + mn);

  for (int off = 32; off > 0; off >>= 1) d += __shfl_down(d, off, 64);

  __shared__ float wsum[4];
  if ((threadIdx.x & 63) == 0) wsum[threadIdx.x >> 6] = d;
  __syncthreads();
  if (threadIdx.x == 0) {
    atomicAdd(out, (wsum[0] + wsum[1] + wsum[2] + wsum[3]) * (1.0f / 32768.0f));
  }
}

// ---------------------------------------------------------------------------
// Fallback (no workspace): full-ref LDS tile, 1 query/thread, atomicAdd.
// ---------------------------------------------------------------------------
__global__ __launch_bounds__(256) void chamfer_simple(
    const float* __restrict__ x, const float* __restrict__ y,
    float* __restrict__ out) {
  const int t   = threadIdx.x;
  const int qc  = blockIdx.x;
  const int b   = blockIdx.y;
  const int dir = blockIdx.z;

  const float* qarr = dir ? y : x;
  const float* rarr = dir ? x : y;
  const float* qb = qarr + (size_t)b * N_PTS * 3;
  const float* rb = rarr + (size_t)b * N_PTS * 3;

  __shared__ float4 s[N_PTS];
  for (int i = t; i < N_PTS; i += 256) {
    const float rx = rb[i * 3], ry = rb[i * 3 + 1], rz = rb[i * 3 + 2];
    s[i] = make_float4(rx, ry, rz, rx * rx + ry * ry + rz * rz);
  }
  __syncthreads();

  const int j = qc * 256 + t;
  const float qx = qb[j * 3], qy = qb[j * 3 + 1], qz = qb[j * 3 + 2];
  const float q2 = qx * qx + qy * qy + qz * qz;
  float m = 3.4e38f;
#pragma unroll 8
  for (int i = 0; i < N_PTS; ++i) {
    const float4 rp = s[i];
    const float cross = qx * rp.x + qy * rp.y + qz * rp.z;
    m = fminf(m, fmaf(-2.0f, cross, rp.w));
  }
  float d = sqrtf(EPSF + fmaxf(q2 + m, 0.0f));

  for (int off = 32; off > 0; off >>= 1) d += __shfl_down(d, off, 64);

  __shared__ float wsum[4];
  if ((t & 63) == 0) wsum[t >> 6] = d;
  __syncthreads();
  if (t == 0) {
    atomicAdd(out, (wsum[0] + wsum[1] + wsum[2] + wsum[3]) * (1.0f / 32768.0f));
  }
}

extern "C" void kernel_launch(void* const* d_in, const int* in_sizes, int n_in,
                              void* d_out, int out_size, void* d_ws, size_t ws_size,
                              hipStream_t stream) {
  const float* x = (const float*)d_in[0];
  const float* y = (const float*)d_in[1];
  float* out = (float*)d_out;

  // d_out is re-poisoned to 0xAA before every timed replay; zero it first.
  hipMemsetAsync(out, 0, sizeof(float) * out_size, stream);

  const size_t ws_need = (size_t)2 * BT * RC * N_PTS * sizeof(float);  // 4 MiB
  if (ws_size >= ws_need) {
    chamfer_stage<<<dim3(RC, BT, 2), 128, 0, stream>>>(x, y, (float*)d_ws);
    chamfer_reduce<<<dim3(256), 256, 0, stream>>>((const float*)d_ws, out);
  } else {
    chamfer_simple<<<dim3(4, BT, 2), 256, 0, stream>>>(x, y, out);
  }
}

// Round 3
// 68.348 us; speedup vs baseline: 1.1164x; 1.0515x over previous
//
#include <hip/hip_runtime.h>
#include <math.h>

#define EPSF 1e-6f
#define N_PTS 1024
#define BT 32
#define RC 16          // ref chunks per (batch, dir); chunk = 64 points
#define CHUNK 64

// ---------------------------------------------------------------------------
// Stage: grid (16 ref-chunks, 32 batches, 2 directions) x 128 threads.
// Q=8 queries/thread (block covers all 1024 queries of its batch).
// Ref chunk (64 pts) staged in LDS as float4(-2rx,-2ry,-2rz,r2); one
// broadcast ds_read_b128 per ref serves 8 queries. Inner pair is a pure
// 3-FMA chain + min = 4 VALU ops/pair (q2 hoisted out of the min):
//   v = ((r2 - 2qx*rx) - 2qy*ry) - 2qz*rz ; m = min(m, v)
// 1024 blocks -> 4 blocks/CU, 2 waves/SIMD: VALU-bound ~3.4us/CU,
// LDS pipe ~2.6us/CU hidden under VALU.
// Writes clamped min-sq partials to ws[(dirb*RC+rc)*1024 + q] (coalesced).
// ---------------------------------------------------------------------------
__global__ __launch_bounds__(128) void chamfer_stage(
    const float* __restrict__ x, const float* __restrict__ y,
    float* __restrict__ ws) {
  const int t   = threadIdx.x;
  const int rc  = blockIdx.x;   // 0..15
  const int b   = blockIdx.y;   // 0..31
  const int dir = blockIdx.z;   // 0: query=x ref=y ; 1: swapped

  const float* qarr = dir ? y : x;
  const float* rarr = dir ? x : y;
  const float* qb = qarr + (size_t)b * (N_PTS * 3);
  const float* rb = rarr + (size_t)b * (N_PTS * 3) + (size_t)rc * (CHUNK * 3);

  __shared__ float4 s[CHUNK];
  if (t < CHUNK) {
    const float rx = rb[t * 3 + 0];
    const float ry = rb[t * 3 + 1];
    const float rz = rb[t * 3 + 2];
    s[t] = make_float4(-2.0f * rx, -2.0f * ry, -2.0f * rz,
                       rx * rx + ry * ry + rz * rz);
  }
  __syncthreads();

  float qx[8], qy[8], qz[8], q2[8], m[8];
#pragma unroll
  for (int k = 0; k < 8; ++k) {
    const int j = t + 128 * k;
    qx[k] = qb[j * 3 + 0];
    qy[k] = qb[j * 3 + 1];
    qz[k] = qb[j * 3 + 2];
    q2[k] = qx[k] * qx[k] + qy[k] * qy[k] + qz[k] * qz[k];
    m[k] = 3.4e38f;
  }

#pragma unroll 8
  for (int i = 0; i < CHUNK; ++i) {
    const float4 rp = s[i];
#pragma unroll
    for (int k = 0; k < 8; ++k) {
      float v = fmaf(qx[k], rp.x, rp.w);   // r2 - 2*qx*rx
      v = fmaf(qy[k], rp.y, v);
      v = fmaf(qz[k], rp.z, v);
      m[k] = fminf(m[k], v);
    }
  }

  float* wbase = ws + ((size_t)(dir * BT + b) * RC + rc) * N_PTS;
#pragma unroll
  for (int k = 0; k < 8; ++k) {
    const int j = t + 128 * k;
    wbase[j] = fmaxf(q2[k] + m[k], 0.0f);  // clamp commutes with min
  }
}

// ---------------------------------------------------------------------------
// Reduce: 65536 (dirb, query) entries, 256 blocks x 256 threads.
// 16 coalesced loads/thread (stride 1024 over rc), min, sqrt(eps+.),
// wave+block sum, one scaled atomicAdd per block.
// ---------------------------------------------------------------------------
__global__ __launch_bounds__(256) void chamfer_reduce(
    const float* __restrict__ ws, float* __restrict__ out) {
  const int g = blockIdx.x * 256 + threadIdx.x;  // 0..65535
  const int dirb = g >> 10;
  const int q = g & (N_PTS - 1);
  const float* base = ws + (size_t)dirb * RC * N_PTS + q;
  float mn = base[0];
#pragma unroll
  for (int r = 1; r < RC; ++r) mn = fminf(mn, base[r * N_PTS]);
  float d = sqrtf(EPSF + mn);

  for (int off = 32; off > 0; off >>= 1) d += __shfl_down(d, off, 64);

  __shared__ float wsum[4];
  if ((threadIdx.x & 63) == 0) wsum[threadIdx.x >> 6] = d;
  __syncthreads();
  if (threadIdx.x == 0) {
    atomicAdd(out, (wsum[0] + wsum[1] + wsum[2] + wsum[3]) * (1.0f / 32768.0f));
  }
}

// ---------------------------------------------------------------------------
// Fallback (no workspace): full-ref LDS tile, 1 query/thread, atomicAdd.
// ---------------------------------------------------------------------------
__global__ __launch_bounds__(256) void chamfer_simple(
    const float* __restrict__ x, const float* __restrict__ y,
    float* __restrict__ out) {
  const int t   = threadIdx.x;
  const int qc  = blockIdx.x;
  const int b   = blockIdx.y;
  const int dir = blockIdx.z;

  const float* qarr = dir ? y : x;
  const float* rarr = dir ? x : y;
  const float* qb = qarr + (size_t)b * N_PTS * 3;
  const float* rb = rarr + (size_t)b * N_PTS * 3;

  __shared__ float4 s[N_PTS];
  for (int i = t; i < N_PTS; i += 256) {
    const float rx = rb[i * 3], ry = rb[i * 3 + 1], rz = rb[i * 3 + 2];
    s[i] = make_float4(-2.0f * rx, -2.0f * ry, -2.0f * rz,
                       rx * rx + ry * ry + rz * rz);
  }
  __syncthreads();

  const int j = qc * 256 + t;
  const float qx = qb[j * 3], qy = qb[j * 3 + 1], qz = qb[j * 3 + 2];
  const float q2 = qx * qx + qy * qy + qz * qz;
  float m = 3.4e38f;
#pragma unroll 8
  for (int i = 0; i < N_PTS; ++i) {
    const float4 rp = s[i];
    float v = fmaf(qx, rp.x, rp.w);
    v = fmaf(qy, rp.y, v);
    v = fmaf(qz, rp.z, v);
    m = fminf(m, v);
  }
  float d = sqrtf(EPSF + fmaxf(q2 + m, 0.0f));

  for (int off = 32; off > 0; off >>= 1) d += __shfl_down(d, off, 64);

  __shared__ float wsum[4];
  if ((t & 63) == 0) wsum[t >> 6] = d;
  __syncthreads();
  if (t == 0) {
    atomicAdd(out, (wsum[0] + wsum[1] + wsum[2] + wsum[3]) * (1.0f / 32768.0f));
  }
}

extern "C" void kernel_launch(void* const* d_in, const int* in_sizes, int n_in,
                              void* d_out, int out_size, void* d_ws, size_t ws_size,
                              hipStream_t stream) {
  const float* x = (const float*)d_in[0];
  const float* y = (const float*)d_in[1];
  float* out = (float*)d_out;

  // d_out is re-poisoned to 0xAA before every timed replay; zero it first.
  hipMemsetAsync(out, 0, sizeof(float) * out_size, stream);

  const size_t ws_need = (size_t)2 * BT * RC * N_PTS * sizeof(float);  // 4 MiB
  if (ws_size >= ws_need) {
    chamfer_stage<<<dim3(RC, BT, 2), 128, 0, stream>>>(x, y, (float*)d_ws);
    chamfer_reduce<<<dim3(256), 256, 0, stream>>>((const float*)d_ws, out);
  } else {
    chamfer_simple<<<dim3(4, BT, 2), 256, 0, stream>>>(x, y, out);
  }
}

// Round 4
// 66.982 us; speedup vs baseline: 1.1392x; 1.0204x over previous
//
#include <hip/hip_runtime.h>
#include <math.h>

#define EPSF 1e-6f
#define N_PTS 1024
#define BT 32
#define RC 16          // ref chunks per (batch, dir); chunk = 64 points
#define CHUNK 64

// ---------------------------------------------------------------------------
// Stage: grid (16 ref-chunks, 32 batches, 2 directions) x 128 threads.
// Q=8 queries/thread (block covers all 1024 queries of its batch).
// Ref chunk (64 pts) staged in LDS as float4(-2rx,-2ry,-2rz,r2); one
// broadcast ds_read_b128 per ref serves 8 queries. Refs processed in PAIRS:
//   v0 = 3-FMA chain(ref i), v1 = 3-FMA chain(ref i+1),
//   m  = fminf(m, fminf(v0, v1))        -> single v_min3_f32
// = 7 VALU inst per 2 pairs (was 8), and min-chain depth halves.
// q2 hoisted out of the min; clamp commutes with min.
// 1024 blocks -> 4 blocks/CU, 2 waves/SIMD; LDS pipe ~2.6us hidden.
// Writes min-sq partials to ws[(dirb*RC+rc)*1024 + q] (coalesced).
// ---------------------------------------------------------------------------
__global__ __launch_bounds__(128) void chamfer_stage(
    const float* __restrict__ x, const float* __restrict__ y,
    float* __restrict__ ws) {
  const int t   = threadIdx.x;
  const int rc  = blockIdx.x;   // 0..15
  const int b   = blockIdx.y;   // 0..31
  const int dir = blockIdx.z;   // 0: query=x ref=y ; 1: swapped

  const float* qarr = dir ? y : x;
  const float* rarr = dir ? x : y;
  const float* qb = qarr + (size_t)b * (N_PTS * 3);
  const float* rb = rarr + (size_t)b * (N_PTS * 3) + (size_t)rc * (CHUNK * 3);

  __shared__ float4 s[CHUNK];
  if (t < CHUNK) {
    const float rx = rb[t * 3 + 0];
    const float ry = rb[t * 3 + 1];
    const float rz = rb[t * 3 + 2];
    s[t] = make_float4(-2.0f * rx, -2.0f * ry, -2.0f * rz,
                       rx * rx + ry * ry + rz * rz);
  }
  __syncthreads();

  float qx[8], qy[8], qz[8], q2[8], m[8];
#pragma unroll
  for (int k = 0; k < 8; ++k) {
    const int j = t + 128 * k;
    qx[k] = qb[j * 3 + 0];
    qy[k] = qb[j * 3 + 1];
    qz[k] = qb[j * 3 + 2];
    q2[k] = qx[k] * qx[k] + qy[k] * qy[k] + qz[k] * qz[k];
    m[k] = 3.4e38f;
  }

#pragma unroll 4
  for (int i = 0; i < CHUNK; i += 2) {
    const float4 r0 = s[i];
    const float4 r1 = s[i + 1];
#pragma unroll
    for (int k = 0; k < 8; ++k) {
      float v0 = fmaf(qx[k], r0.x, r0.w);
      v0 = fmaf(qy[k], r0.y, v0);
      v0 = fmaf(qz[k], r0.z, v0);
      float v1 = fmaf(qx[k], r1.x, r1.w);
      v1 = fmaf(qy[k], r1.y, v1);
      v1 = fmaf(qz[k], r1.z, v1);
      m[k] = fminf(m[k], fminf(v0, v1));  // -> v_min3_f32
    }
  }

  float* wbase = ws + ((size_t)(dir * BT + b) * RC + rc) * N_PTS;
#pragma unroll
  for (int k = 0; k < 8; ++k) {
    const int j = t + 128 * k;
    wbase[j] = fmaxf(q2[k] + m[k], 0.0f);
  }
}

// ---------------------------------------------------------------------------
// Reduce: 65536 (dirb, query) entries, 2 queries/thread via float2 loads.
// 128 blocks x 256 threads; 16 coalesced 8B loads/thread (stride 1024 over
// rc), componentwise min, sqrt(eps+.), wave+block sum, one atomicAdd/block.
// ---------------------------------------------------------------------------
__global__ __launch_bounds__(256) void chamfer_reduce(
    const float* __restrict__ ws, float* __restrict__ out) {
  const int g = blockIdx.x * 256 + threadIdx.x;   // 0..32767 (pairs)
  const float2* base = (const float2*)ws + g;     // pair-indexed
  float2 mn = base[0];
#pragma unroll
  for (int r = 1; r < RC; ++r) {
    const float2 v = base[(size_t)r * (N_PTS / 2) * (2 * BT / RC) * (RC / (2 * BT)) ];
    (void)v; break;  // placeholder never taken (RC loop below is the real one)
  }
  // real loop: rows are rc within this (dirb) band. g encodes (dirb, qpair):
  // dirb = g >> 9, qpair = g & 511. Row stride in float2 units = 512.
  {
    const int dirb = g >> 9;
    const int qp = g & 511;
    const float2* p = (const float2*)ws + (size_t)dirb * RC * 512 + qp;
    mn = p[0];
#pragma unroll
    for (int r = 1; r < RC; ++r) {
      const float2 v = p[(size_t)r * 512];
      mn.x = fminf(mn.x, v.x);
      mn.y = fminf(mn.y, v.y);
    }
  }
  float d = sqrtf(EPSF + mn.x) + sqrtf(EPSF + mn.y);

  for (int off = 32; off > 0; off >>= 1) d += __shfl_down(d, off, 64);

  __shared__ float wsum[4];
  if ((threadIdx.x & 63) == 0) wsum[threadIdx.x >> 6] = d;
  __syncthreads();
  if (threadIdx.x == 0) {
    atomicAdd(out, (wsum[0] + wsum[1] + wsum[2] + wsum[3]) * (1.0f / 32768.0f));
  }
}

// ---------------------------------------------------------------------------
// Fallback (no workspace): full-ref LDS tile, 1 query/thread, atomicAdd.
// ---------------------------------------------------------------------------
__global__ __launch_bounds__(256) void chamfer_simple(
    const float* __restrict__ x, const float* __restrict__ y,
    float* __restrict__ out) {
  const int t   = threadIdx.x;
  const int qc  = blockIdx.x;
  const int b   = blockIdx.y;
  const int dir = blockIdx.z;

  const float* qarr = dir ? y : x;
  const float* rarr = dir ? x : y;
  const float* qb = qarr + (size_t)b * N_PTS * 3;
  const float* rb = rarr + (size_t)b * N_PTS * 3;

  __shared__ float4 s[N_PTS];
  for (int i = t; i < N_PTS; i += 256) {
    const float rx = rb[i * 3], ry = rb[i * 3 + 1], rz = rb[i * 3 + 2];
    s[i] = make_float4(-2.0f * rx, -2.0f * ry, -2.0f * rz,
                       rx * rx + ry * ry + rz * rz);
  }
  __syncthreads();

  const int j = qc * 256 + t;
  const float qx = qb[j * 3], qy = qb[j * 3 + 1], qz = qb[j * 3 + 2];
  const float q2 = qx * qx + qy * qy + qz * qz;
  float m = 3.4e38f;
#pragma unroll 8
  for (int i = 0; i < N_PTS; i += 2) {
    const float4 r0 = s[i];
    const float4 r1 = s[i + 1];
    float v0 = fmaf(qx, r0.x, r0.w);
    v0 = fmaf(qy, r0.y, v0);
    v0 = fmaf(qz, r0.z, v0);
    float v1 = fmaf(qx, r1.x, r1.w);
    v1 = fmaf(qy, r1.y, v1);
    v1 = fmaf(qz, r1.z, v1);
    m = fminf(m, fminf(v0, v1));
  }
  float d = sqrtf(EPSF + fmaxf(q2 + m, 0.0f));

  for (int off = 32; off > 0; off >>= 1) d += __shfl_down(d, off, 64);

  __shared__ float wsum[4];
  if ((t & 63) == 0) wsum[t >> 6] = d;
  __syncthreads();
  if (t == 0) {
    atomicAdd(out, (wsum[0] + wsum[1] + wsum[2] + wsum[3]) * (1.0f / 32768.0f));
  }
}

extern "C" void kernel_launch(void* const* d_in, const int* in_sizes, int n_in,
                              void* d_out, int out_size, void* d_ws, size_t ws_size,
                              hipStream_t stream) {
  const float* x = (const float*)d_in[0];
  const float* y = (const float*)d_in[1];
  float* out = (float*)d_out;

  // d_out is re-poisoned to 0xAA before every timed replay; zero it first.
  hipMemsetAsync(out, 0, sizeof(float) * out_size, stream);

  const size_t ws_need = (size_t)2 * BT * RC * N_PTS * sizeof(float);  // 4 MiB
  if (ws_size >= ws_need) {
    chamfer_stage<<<dim3(RC, BT, 2), 128, 0, stream>>>(x, y, (float*)d_ws);
    chamfer_reduce<<<dim3(128), 256, 0, stream>>>((const float*)d_ws, out);
  } else {
    chamfer_simple<<<dim3(4, BT, 2), 256, 0, stream>>>(x, y, out);
  }
}